// Round 1
// baseline (10969.096 us; speedup 1.0000x reference)
//
#include <hip/hip_runtime.h>

// LSTM_36807869726767 — round 5: 128 fat blocks, split h_hi/h_lo, k-major LDS.
// Round-4 analysis: 28K cyc/step, ~80% stall at 1 wave/SIMD (exposed L3/L2
// latency + 256-block barrier + 8MB/XCD/step L2 broadcast + 256 v_perm/step).
// This round:
//  - 128 blocks x 512 thr (8 waves): 2 waves/SIMD (latency hiding), barrier
//    participants halved, L2 h-broadcast per XCD halved. Same total waves.
//  - h state as SEPARATE h_hi/h_lo f16 arrays: loads feed MFMA directly,
//    zero v_perm. Writers pair-pack (one shfl) into u32 agent-scope stores
//    (same write-once-slot coherence scheme as round 4 — proven correct).
//  - weights k-major [kchunk][32 rows][8]: zero pad, conflict-free (2-way),
//    Wsh+Wsl = 128KB LDS. E-part weights streamed from L2 (Wge, k-major,
//    32KB/block, loaded pre-barrier where latency is hidden by the spin).
//  - fast sigmoid/tanh (__expf + v_rcp), s_sleep 2, bias folded into acc init.
// B=64, S=512, E=512, H=1024, NCLS=10, PAD=0. All float I/O f32.

typedef _Float16 f16;
typedef __attribute__((ext_vector_type(8))) _Float16 f16x8;
typedef __attribute__((ext_vector_type(4))) _Float16 f16x4;
typedef __attribute__((ext_vector_type(4))) float f32x4;

#define Bn 64
#define Sn 512
#define En 512
#define Hn 1024
#define NBLK 128

__device__ __forceinline__ float fsig(float x) {
    return __builtin_amdgcn_rcpf(1.f + __expf(-x));
}
__device__ __forceinline__ float ftanh(float x) {
    return 2.f * __builtin_amdgcn_rcpf(1.f + __expf(-2.f * x)) - 1.f;
}

// ------------------------------------------------- gather e -> f16 [t][b][k]
__global__ __launch_bounds__(256) void gather_e_k(
    const int* __restrict__ x, const float* __restrict__ emb,
    f16* __restrict__ e16)
{
    size_t g = (size_t)blockIdx.x * 256 + threadIdx.x;
    int row = (int)(g >> 6);          // t*64 + b
    int ko  = (int)(g & 63) * 8;
    int t = row >> 6, b = row & 63;
    int tok = x[b * Sn + t];
    float4 a  = *(const float4*)&emb[(size_t)tok * En + ko];
    float4 a2 = *(const float4*)&emb[(size_t)tok * En + ko + 4];
    float v[8] = {a.x, a.y, a.z, a.w, a2.x, a2.y, a2.z, a2.w};
    f16x8 h;
    #pragma unroll
    for (int i = 0; i < 8; ++i) h[i] = (f16)v[i];
    *(f16x8*)&e16[(size_t)row * En + ko] = h;
}

// ------------------------------------------------------------- Wa f32 -> f16
__global__ __launch_bounds__(256) void split_wa_k(
    const float* __restrict__ Wa, f16* __restrict__ hi)
{
    size_t g = ((size_t)blockIdx.x * 256 + threadIdx.x) * 8;
    float4 a = *(const float4*)&Wa[g];
    float4 b = *(const float4*)&Wa[g + 4];
    float v[8] = {a.x, a.y, a.z, a.w, b.x, b.y, b.z, b.w};
    f16x8 h;
    #pragma unroll
    for (int i = 0; i < 8; ++i) h[i] = (f16)v[i];
    *(f16x8*)&hi[g] = h;
}

// ----------------------------- e-part weights, k-major per block:
// Wge[bk][ck 0..63][n 0..31][8] = (f16)Wg[j(bk,n)][ck*8 + 0..7]
// j(bk,n) = gate(n)*1024 + bk*8 + (n>>4)*4 + (n&3), gate(n) = (n&15)>>2
__global__ __launch_bounds__(256) void wge_prep_k(
    const float* __restrict__ Wg, f16* __restrict__ Wge)
{
    int g = blockIdx.x * 256 + threadIdx.x;   // 128 * 2048 cells
    int bk  = g >> 11;
    int rem = g & 2047;
    int n  = rem & 31;
    int ck = rem >> 5;
    int j = ((n & 15) >> 2) * 1024 + bk * 8 + (n >> 4) * 4 + (n & 3);
    const float* src = Wg + (size_t)j * 1536 + ck * 8;
    float4 a = *(const float4*)src;
    float4 b = *(const float4*)(src + 4);
    float v[8] = {a.x, a.y, a.z, a.w, b.x, b.y, b.z, b.w};
    f16x8 h;
    #pragma unroll
    for (int i = 0; i < 8; ++i) h[i] = (f16)v[i];
    *(f16x8*)&Wge[(size_t)g * 8] = h;
}

// ------------------------------------------- persistent LSTM recurrence
// 128 blocks x 512 thr. Block bk owns dims d0=8*bk..d0+7 (32 gate rows).
// Wave w: mg=w&3 (16 batches), ng=w>>2 (16 gate rows). h state in write-once
// slots: h_hi/h_lo[slot][b][k] f16; slot t = state entering step t; slot 0
// zeroed; step t writes slot t+1 via relaxed agent-scope u32 stores
// (write-through to coherence point; readers use normal cached loads).
__global__ __launch_bounds__(512, 2) void lstm_persist_k(
    const f16* __restrict__ e16,      // [512*64][512]
    const f16* __restrict__ Wge,      // [128][64][32][8]
    const float* __restrict__ Wg,     // [4096][1536] f32
    const float* __restrict__ bg,     // [4096]
    f16* __restrict__ h_hi,           // [513][64][1024]
    f16* __restrict__ h_lo,           // [513][64][1024]
    unsigned* __restrict__ bar)       // [8*32] group counters + [512] root
{
    // k-major: [kchunk 128][row 32][8]  -> 64KB each, zero pad, 2-way banks
    __shared__ f16 Wsh[128 * 32 * 8];
    __shared__ f16 Wsl[128 * 32 * 8];

    const int tid = threadIdx.x;
    const int bk  = blockIdx.x;     // 0..127
    const int d0  = bk * 8;

    // ---- one-time: stage h-part weight rows (cols 512..1535) hi/lo, k-major
    {
        int n = tid >> 4, l16 = tid & 15;
        int j = ((n & 15) >> 2) * 1024 + d0 + (n >> 4) * 4 + (n & 3);
        const float* src = Wg + (size_t)j * 1536 + 512;
        for (int k = l16 * 4; k < 1024; k += 64) {
            float4 v = *(const float4*)&src[k];
            float vv[4] = {v.x, v.y, v.z, v.w};
            #pragma unroll
            for (int i = 0; i < 4; ++i) {
                int kk = k + i;
                f16 hv = (f16)vv[i];
                f16 lv = (f16)(vv[i] - (float)hv);
                int idx = ((kk >> 3) * 32 + n) * 8 + (kk & 7);
                Wsh[idx] = hv;
                Wsl[idx] = lv;
            }
        }
    }
    __syncthreads();

    const int lane = tid & 63;
    const int w    = tid >> 6;      // 0..7
    const int mg   = w & 3;         // batch group
    const int ng   = w >> 2;        // gate-row group (0..1)
    const int cl   = lane & 15;
    const int q    = lane >> 4;
    const int b    = mg * 16 + cl;  // A-operand batch row
    const int ko   = q * 8;
    const int co   = cl & 3;
    const int jcol = (cl >> 2) * 1024 + d0 + ng * 4 + co;
    const float bgv = bg[jcol];

    const int wrow = (q * 32 + ng * 16 + cl) * 8;  // lane base into k-major
    const f16* Wh_r = &Wsh[wrow];
    const f16* Wl_r = &Wsl[wrow];
    const f16* Be   = Wge + (size_t)bk * (64 * 32 * 8) + wrow;

    unsigned* grp  = &bar[(bk >> 4) * 32];   // 8 groups of 16 blocks
    unsigned* root = &bar[512];

    float cst[4] = {0.f, 0.f, 0.f, 0.f};
    int bail = 0;

    for (int t = 0; t < Sn; ++t) {
        // ---- e-part (independent of h) — runs while barrier settles
        const f16* Ae = e16 + ((size_t)t * 64 + b) * En + ko;
        f32x4 accE = {bgv, bgv, bgv, bgv};   // bias folded in
        #pragma unroll 4
        for (int ks = 0; ks < 16; ++ks) {
            f16x8 a  = *(const f16x8*)&Ae[ks * 32];
            f16x8 bb = *(const f16x8*)&Be[ks * 1024];
            accE = __builtin_amdgcn_mfma_f32_16x16x32_f16(a, bb, accE, 0, 0, 0);
        }

        // ---- wait for step t-1 (root >= 8*t); relaxed spin, no acquire
        if (tid == 0 && t > 0 && !bail) {
            unsigned tgt = 8u * (unsigned)t;
            long spins = 0;
            while (__hip_atomic_load(root, __ATOMIC_RELAXED,
                                     __HIP_MEMORY_SCOPE_AGENT) < tgt) {
                __builtin_amdgcn_s_sleep(2);
                if (++spins > (1L << 24)) { bail = 1; break; }
            }
        }
        __syncthreads();
        __builtin_amdgcn_fence(__ATOMIC_ACQUIRE, "workgroup"); // no buffer_inv
        __asm__ __volatile__("" ::: "memory");

        // ---- h-part: normal cached loads of write-once slot t (L2 dedups)
        const f16* Ah = h_hi + ((size_t)t * 64 + b) * Hn + ko;
        const f16* Al = h_lo + ((size_t)t * 64 + b) * Hn + ko;
        f32x4 acc1 = {0.f, 0.f, 0.f, 0.f};
        f32x4 acc2 = {0.f, 0.f, 0.f, 0.f};
        f32x4 acc3 = {0.f, 0.f, 0.f, 0.f};
        #pragma unroll 4
        for (int ks = 0; ks < 32; ++ks) {
            f16x8 ah = *(const f16x8*)&Ah[ks * 32];
            f16x8 al = *(const f16x8*)&Al[ks * 32];
            f16x8 bh = *(const f16x8*)&Wh_r[ks * 1024];
            f16x8 bl = *(const f16x8*)&Wl_r[ks * 1024];
            acc1 = __builtin_amdgcn_mfma_f32_16x16x32_f16(ah, bh, acc1, 0, 0, 0);
            acc2 = __builtin_amdgcn_mfma_f32_16x16x32_f16(ah, bl, acc2, 0, 0, 0);
            acc3 = __builtin_amdgcn_mfma_f32_16x16x32_f16(al, bh, acc3, 0, 0, 0);
        }
        f32x4 acc;
        #pragma unroll
        for (int r = 0; r < 4; ++r)
            acc[r] = (accE[r] + acc1[r]) + (acc2[r] + acc3[r]);

        // ---- cell update. D: col=cl (gate jcol), row=q*4+r (batch mg*16+q*4+r)
        #pragma unroll
        for (int r = 0; r < 4; ++r) {
            float av = acc[r];
            float iv = __shfl(av, (lane & 48) | co,      64);
            float fv = __shfl(av, (lane & 48) | 4 | co,  64);
            float gv = __shfl(av, (lane & 48) | 8 | co,  64);
            float ov = __shfl(av, (lane & 48) | 12 | co, 64);
            if (cl < 4) {
                float i_ = fsig(iv);
                float f_ = fsig(fv);
                float g_ = ftanh(gv);
                float o_ = fsig(ov);
                float cn = f_ * cst[r] + i_ * g_;
                cst[r] = cn;
                float hn = o_ * ftanh(cn);
                f16 hh = (f16)hn;
                f16 hl = (f16)(hn - (float)hh);
                unsigned my = (unsigned)__builtin_bit_cast(unsigned short, hh)
                            | ((unsigned)__builtin_bit_cast(unsigned short, hl) << 16);
                // pair-pack with neighbor dim: even co -> h_hi word, odd -> h_lo
                unsigned nb = __shfl(my, lane ^ 1, 64);
                unsigned pk = (co & 1) ? ((nb >> 16) | (my & 0xffff0000u))
                                       : ((my & 0xffffu) | (nb << 16));
                unsigned* dstbase = (co & 1) ? (unsigned*)h_lo : (unsigned*)h_hi;
                int br = mg * 16 + q * 4 + r;
                int du = (d0 + ng * 4 + co) >> 1;
                __hip_atomic_store(&dstbase[((size_t)(t + 1) * 64 + br) * (Hn / 2) + du],
                                   pk, __ATOMIC_RELAXED, __HIP_MEMORY_SCOPE_AGENT);
            }
        }

        // ---- arrive: __syncthreads drains vmcnt(0) per wave (stores acked)
        __syncthreads();
        __asm__ __volatile__("" ::: "memory");
        if (tid == 0) {
            unsigned prev = __hip_atomic_fetch_add(grp, 1u, __ATOMIC_RELAXED,
                                                   __HIP_MEMORY_SCOPE_AGENT);
            if ((prev & 15u) == 15u)   // 16th arrival of this step in group
                __hip_atomic_fetch_add(root, 1u, __ATOMIC_RELAXED,
                                       __HIP_MEMORY_SCOPE_AGENT);
        }
    }
}

// ---------------------------------------------------------------- energy GEMM
// rows r = t*64+b (h_hi linear row r+64); energy[r] += tanh(row.Wa[d]) * va[d]
__global__ __launch_bounds__(256) void energy_k(
    const f16* __restrict__ h_hi,       // [513*64][1024]
    const f16* __restrict__ Wa_hi,      // [H][H]
    const float* __restrict__ va,       // [H]
    float* __restrict__ energy)         // [B*S] (r-indexed), pre-zeroed
{
    __shared__ f16 Was[128][136];
    const int bid = blockIdx.x;
    const int rb = bid >> 3;
    const int nb = bid & 7;
    const int tid = threadIdx.x;
    const int lane = tid & 63, w = tid >> 6, cl = lane & 15, q = lane >> 4;
    const int r0 = rb * 64 + w * 16 + cl;

    f32x4 acc[8];
    #pragma unroll
    for (int i = 0; i < 8; ++i) acc[i] = (f32x4){0.f, 0.f, 0.f, 0.f};

    for (int kc = 0; kc < 8; ++kc) {
        __syncthreads();
        for (int i = tid; i < 128 * 16; i += 256) {
            int dd = i >> 4;
            int kv = (i & 15) * 8;
            *(f16x8*)&Was[dd][kv] =
                *(const f16x8*)&Wa_hi[(size_t)(nb * 128 + dd) * Hn + kc * 128 + kv];
        }
        __syncthreads();
        const f16* A = h_hi + (size_t)(r0 + 64) * Hn + kc * 128;
        #pragma unroll
        for (int ks = 0; ks < 4; ++ks) {
            f16x8 ah = *(const f16x8*)&A[ks * 32 + q * 8];
            #pragma unroll
            for (int nt = 0; nt < 8; ++nt) {
                f16x8 bb = *(const f16x8*)&Was[nt * 16 + cl][ks * 32 + q * 8];
                acc[nt] = __builtin_amdgcn_mfma_f32_16x16x32_f16(ah, bb, acc[nt], 0, 0, 0);
            }
        }
    }

    float rowsum[4] = {0.f, 0.f, 0.f, 0.f};
    #pragma unroll
    for (int nt = 0; nt < 8; ++nt) {
        float vv = va[nb * 128 + nt * 16 + cl];
        #pragma unroll
        for (int r = 0; r < 4; ++r)
            rowsum[r] += tanhf(acc[nt][r]) * vv;
    }
    #pragma unroll
    for (int m = 1; m < 16; m <<= 1)
        #pragma unroll
        for (int r = 0; r < 4; ++r)
            rowsum[r] += __shfl_xor(rowsum[r], m, 64);
    if (cl == 0) {
        #pragma unroll
        for (int r = 0; r < 4; ++r)
            atomicAdd(&energy[(size_t)rb * 64 + w * 16 + q * 4 + r], rowsum[r]);
    }
}

// ------------------------------------------------- masked softmax + context
// energy index for (b,s) = s*64 + b
__global__ __launch_bounds__(256) void softctx_k(
    const float* __restrict__ energy, const int* __restrict__ x,
    const f16* __restrict__ h_hi, const f16* __restrict__ h_lo,
    float* __restrict__ context)   // [B][H]
{
    __shared__ float sm[512];
    __shared__ float red[256];
    const int b = blockIdx.x, tid = threadIdx.x;
    const int s0 = tid, s1 = tid + 256;
    float e0 = (x[b * Sn + s0] != 0) ? energy[s0 * 64 + b] : -1e10f;
    float e1 = (x[b * Sn + s1] != 0) ? energy[s1 * 64 + b] : -1e10f;
    red[tid] = fmaxf(e0, e1);
    __syncthreads();
    for (int st = 128; st > 0; st >>= 1) {
        if (tid < st) red[tid] = fmaxf(red[tid], red[tid + st]);
        __syncthreads();
    }
    float M = red[0];
    __syncthreads();
    float p0 = expf(e0 - M), p1 = expf(e1 - M);
    red[tid] = p0 + p1;
    __syncthreads();
    for (int st = 128; st > 0; st >>= 1) {
        if (tid < st) red[tid] += red[tid + st];
        __syncthreads();
    }
    float inv = 1.f / red[0];
    sm[s0] = p0 * inv; sm[s1] = p1 * inv;
    __syncthreads();

    const int d0v = tid * 4;
    float a0 = 0.f, a1 = 0.f, a2 = 0.f, a3 = 0.f;
    for (int s = 0; s < Sn; ++s) {
        float at = sm[s];
        size_t row = ((size_t)(s + 1) * 64 + b) * Hn + d0v;
        f16x4 hv = *(const f16x4*)&h_hi[row];
        f16x4 lv = *(const f16x4*)&h_lo[row];
        a0 += at * ((float)hv[0] + (float)lv[0]);
        a1 += at * ((float)hv[1] + (float)lv[1]);
        a2 += at * ((float)hv[2] + (float)lv[2]);
        a3 += at * ((float)hv[3] + (float)lv[3]);
    }
    float* cp = context + (size_t)b * Hn + d0v;
    cp[0] = a0; cp[1] = a1; cp[2] = a2; cp[3] = a3;
}

// ---------------------------------------------------------------- logits
__global__ __launch_bounds__(256) void logits_k(
    const float* __restrict__ context, const float* __restrict__ WV,
    const float* __restrict__ bV, float* __restrict__ out)
{
    __shared__ float red[10][257];
    const int b = blockIdx.x, tid = threadIdx.x;
    const int d0v = tid * 4;
    float4 cv = *(const float4*)&context[(size_t)b * Hn + d0v];
    #pragma unroll
    for (int cls = 0; cls < 10; ++cls) {
        float4 wv = *(const float4*)&WV[cls * Hn + d0v];
        red[cls][tid] = cv.x * wv.x + cv.y * wv.y + cv.z * wv.z + cv.w * wv.w;
    }
    __syncthreads();
    for (int st = 128; st > 0; st >>= 1) {
        if (tid < st)
            #pragma unroll
            for (int cls = 0; cls < 10; ++cls)
                red[cls][tid] += red[cls][tid + st];
        __syncthreads();
    }
    if (tid < 10) out[b * 10 + tid] = red[tid][0] + bV[tid];
}

// ---------------------------------------------------------------- launch
extern "C" void kernel_launch(void* const* d_in, const int* in_sizes, int n_in,
                              void* d_out, int out_size, void* d_ws, size_t ws_size,
                              hipStream_t stream)
{
    const int*   x   = (const int*)d_in[0];
    const float* emb = (const float*)d_in[1];
    const float* Wg  = (const float*)d_in[2];
    const float* bg  = (const float*)d_in[3];
    const float* Wa  = (const float*)d_in[4];
    const float* va  = (const float*)d_in[5];
    const float* WV  = (const float*)d_in[6];
    const float* bV  = (const float*)d_in[7];
    float* out = (float*)d_out;

    char* ws = (char*)d_ws;
    size_t o = 0;
    auto alloc = [&](size_t bytes) { void* p = ws + o; o += (bytes + 255) & ~(size_t)255; return p; };
    f16*      e16   = (f16*)alloc((size_t)Sn * Bn * En * 2);            // 33.5 MB
    f16*      Wa_hi = (f16*)alloc((size_t)Hn * Hn * 2);                 // 2 MB
    f16*      Wge   = (f16*)alloc((size_t)NBLK * 64 * 32 * 8 * 2);      // 4 MB
    f16*      h_hi  = (f16*)alloc((size_t)(Sn + 1) * Bn * Hn * 2);      // 67.2 MB
    f16*      h_lo  = (f16*)alloc((size_t)(Sn + 1) * Bn * Hn * 2);      // 67.2 MB
    float*    energy= (float*)alloc((size_t)Bn * Sn * 4);
    float*    ctx   = (float*)alloc((size_t)Bn * Hn * 4);
    unsigned* bar   = (unsigned*)alloc(4096);
    // total ~175 MB

    hipMemsetAsync(h_hi, 0, (size_t)Bn * Hn * 2, stream);   // slot 0 = zeros
    hipMemsetAsync(h_lo, 0, (size_t)Bn * Hn * 2, stream);
    hipMemsetAsync(energy, 0, (size_t)Bn * Sn * 4, stream);
    hipMemsetAsync(bar, 0, 4096, stream);

    gather_e_k<<<8192, 256, 0, stream>>>(x, emb, e16);
    split_wa_k<<<512, 256, 0, stream>>>(Wa, Wa_hi);
    wge_prep_k<<<1024, 256, 0, stream>>>(Wg, Wge);

    lstm_persist_k<<<NBLK, 512, 0, stream>>>(e16, Wge, Wg, bg, h_hi, h_lo, bar);

    energy_k<<<512 * 8, 256, 0, stream>>>(h_hi, Wa_hi, va, energy);
    softctx_k<<<Bn, 256, 0, stream>>>(energy, x, h_hi, h_lo, ctx);
    logits_k<<<Bn, 256, 0, stream>>>(ctx, WV, bV, out);
}

// Round 2
// 7722.015 us; speedup vs baseline: 1.4205x; 1.4205x over previous
//
#include <hip/hip_runtime.h>

// LSTM_36807869726767 — round 6: 256 thin blocks (round-4 shape) + round-5 wins.
// Round-5 post-mortem: 128 fat blocks left half the CUs idle and the global
// barrier lockstep defeated 2-wave/SIMD overlap -> per-CU time ~ Nwaves x
// serial wave time -> 1.76x regression. Round-5's verified-good pieces kept:
//  - k-major conflict-free LDS weights (conflicts 1.68e8 -> 9e5)
//  - split h_hi/h_lo (no v_perm on the read path), pair-packed u32 stores
//  - fast sigmoid/tanh, bias folded into accumulator init
// New this round:
//  - 256 blocks x 256 thr (1 wave/SIMD, all 256 CUs) with 32 batch x 32 gate-row
//    blocks: h broadcast per block halves (256KB -> 128KB/step), per-XCD L2
//    service 8MB -> ~5MB/step.
//  - e-part weights streamed from L2 (Wge, k-major, 32KB/block/step) issued
//    BEFORE the spin (overlaps barrier wait); removes round-4's conflicted
//    Wse LDS reads.
// B=64, S=512, E=512, H=1024, NCLS=10, PAD=0. All float I/O f32.

typedef _Float16 f16;
typedef __attribute__((ext_vector_type(8))) _Float16 f16x8;
typedef __attribute__((ext_vector_type(4))) _Float16 f16x4;
typedef __attribute__((ext_vector_type(4))) float f32x4;

#define Bn 64
#define Sn 512
#define En 512
#define Hn 1024

__device__ __forceinline__ float fsig(float x) {
    return __builtin_amdgcn_rcpf(1.f + __expf(-x));
}
__device__ __forceinline__ float ftanh(float x) {
    return 2.f * __builtin_amdgcn_rcpf(1.f + __expf(-2.f * x)) - 1.f;
}

// ------------------------------------------------- gather e -> f16 [t][b][k]
__global__ __launch_bounds__(256) void gather_e_k(
    const int* __restrict__ x, const float* __restrict__ emb,
    f16* __restrict__ e16)
{
    size_t g = (size_t)blockIdx.x * 256 + threadIdx.x;
    int row = (int)(g >> 6);          // t*64 + b
    int ko  = (int)(g & 63) * 8;
    int t = row >> 6, b = row & 63;
    int tok = x[b * Sn + t];
    float4 a  = *(const float4*)&emb[(size_t)tok * En + ko];
    float4 a2 = *(const float4*)&emb[(size_t)tok * En + ko + 4];
    float v[8] = {a.x, a.y, a.z, a.w, a2.x, a2.y, a2.z, a2.w};
    f16x8 h;
    #pragma unroll
    for (int i = 0; i < 8; ++i) h[i] = (f16)v[i];
    *(f16x8*)&e16[(size_t)row * En + ko] = h;
}

// ------------------------------------------------------------- Wa f32 -> f16
__global__ __launch_bounds__(256) void split_wa_k(
    const float* __restrict__ Wa, f16* __restrict__ hi)
{
    size_t g = ((size_t)blockIdx.x * 256 + threadIdx.x) * 8;
    float4 a = *(const float4*)&Wa[g];
    float4 b = *(const float4*)&Wa[g + 4];
    float v[8] = {a.x, a.y, a.z, a.w, b.x, b.y, b.z, b.w};
    f16x8 h;
    #pragma unroll
    for (int i = 0; i < 8; ++i) h[i] = (f16)v[i];
    *(f16x8*)&hi[g] = h;
}

// ----------------------------- e-part weights, k-major per row-group:
// Wge[rg][ck 0..63][n 0..31][8] = (f16)Wg[j(rg,n)][ck*8 + 0..7]
// j(rg,n) = gate(n)*1024 + rg*8 + (n>>4)*4 + (n&3), gate(n) = (n&15)>>2
__global__ __launch_bounds__(256) void wge_prep_k(
    const float* __restrict__ Wg, f16* __restrict__ Wge)
{
    int g = blockIdx.x * 256 + threadIdx.x;   // 128 * 2048 cells
    int rg  = g >> 11;
    int rem = g & 2047;
    int n  = rem & 31;
    int ck = rem >> 5;
    int j = ((n & 15) >> 2) * 1024 + rg * 8 + (n >> 4) * 4 + (n & 3);
    const float* src = Wg + (size_t)j * 1536 + ck * 8;
    float4 a = *(const float4*)src;
    float4 b = *(const float4*)(src + 4);
    float v[8] = {a.x, a.y, a.z, a.w, b.x, b.y, b.z, b.w};
    f16x8 h;
    #pragma unroll
    for (int i = 0; i < 8; ++i) h[i] = (f16)v[i];
    *(f16x8*)&Wge[(size_t)g * 8] = h;
}

// ------------------------------------------- persistent LSTM recurrence
// 256 blocks x 256 thr (4 waves, 1/SIMD, all CUs). Block bk: rg=bk>>1 owns
// h-dims d0=8*rg..d0+7 (32 gate rows); bh=bk&1 owns batches bh*32..+31.
// Wave w: mi=w&1 (16 batches), ni=w>>1 (16 gate rows). h state in write-once
// slots: h_hi/h_lo[slot][b][k] f16; slot t = state entering step t; slot 0
// zeroed; step t writes slot t+1 via relaxed agent-scope u32 stores
// (write-through to coherence point; readers use normal cached loads).
__global__ __launch_bounds__(256) void lstm_persist_k(
    const f16* __restrict__ e16,      // [512*64][512]
    const f16* __restrict__ Wge,      // [128][64][32][8]
    const float* __restrict__ Wg,     // [4096][1536] f32
    const float* __restrict__ bg,     // [4096]
    f16* __restrict__ h_hi,           // [513][64][1024]
    f16* __restrict__ h_lo,           // [513][64][1024]
    unsigned* __restrict__ bar)       // [16*32] group counters + [512] root
{
    // k-major: [kchunk 128][row 32][8] -> 64KB each, zero pad, conflict-free
    __shared__ f16 Wsh[128 * 32 * 8];
    __shared__ f16 Wsl[128 * 32 * 8];

    const int tid = threadIdx.x;
    const int bk  = blockIdx.x;     // 0..255
    const int rg  = bk >> 1;        // row-group 0..127
    const int bh  = bk & 1;         // batch half
    const int d0  = rg * 8;

    // ---- one-time: stage h-part weight rows (cols 512..1535) hi/lo, k-major
    {
        int n = tid >> 3, l8 = tid & 7;
        int j = ((n & 15) >> 2) * 1024 + d0 + (n >> 4) * 4 + (n & 3);
        const float* src = Wg + (size_t)j * 1536 + 512;
        for (int k = l8 * 4; k < 1024; k += 32) {
            float4 v = *(const float4*)&src[k];
            float vv[4] = {v.x, v.y, v.z, v.w};
            #pragma unroll
            for (int i = 0; i < 4; ++i) {
                int kk = k + i;
                f16 hv = (f16)vv[i];
                f16 lv = (f16)(vv[i] - (float)hv);
                int idx = ((kk >> 3) * 32 + n) * 8 + (kk & 7);
                Wsh[idx] = hv;
                Wsl[idx] = lv;
            }
        }
    }
    __syncthreads();

    const int lane = tid & 63;
    const int w    = tid >> 6;      // 0..3
    const int mi   = w & 1;         // batch tile
    const int ni   = w >> 1;        // gate-row tile
    const int cl   = lane & 15;
    const int q    = lane >> 4;
    const int b    = bh * 32 + mi * 16 + cl;   // A-operand batch row
    const int ko   = q * 8;
    const int co   = cl & 3;
    const int jcol = (cl >> 2) * 1024 + d0 + ni * 4 + co;
    const float bgv = bg[jcol];

    const int wrow = (q * 32 + ni * 16 + cl) * 8;  // lane base into k-major
    const f16* Wh_r = &Wsh[wrow];
    const f16* Wl_r = &Wsl[wrow];
    const f16* Be   = Wge + (size_t)rg * (64 * 32 * 8) + wrow;

    unsigned* grp  = &bar[(bk >> 4) * 32];   // 16 groups of 16 blocks
    unsigned* root = &bar[512];

    float cst[4] = {0.f, 0.f, 0.f, 0.f};
    int bail = 0;

    for (int t = 0; t < Sn; ++t) {
        // ---- e-part (independent of h) — runs while barrier settles
        const f16* Ae = e16 + ((size_t)t * 64 + b) * En + ko;
        f32x4 accE = {bgv, bgv, bgv, bgv};   // bias folded in
        #pragma unroll 4
        for (int ks = 0; ks < 16; ++ks) {
            f16x8 a  = *(const f16x8*)&Ae[ks * 32];
            f16x8 bb = *(const f16x8*)&Be[ks * 1024];
            accE = __builtin_amdgcn_mfma_f32_16x16x32_f16(a, bb, accE, 0, 0, 0);
        }

        // ---- wait for step t-1 (root >= 16*t); relaxed spin, no acquire
        if (tid == 0 && t > 0 && !bail) {
            unsigned tgt = 16u * (unsigned)t;
            long spins = 0;
            while (__hip_atomic_load(root, __ATOMIC_RELAXED,
                                     __HIP_MEMORY_SCOPE_AGENT) < tgt) {
                __builtin_amdgcn_s_sleep(2);
                if (++spins > (1L << 24)) { bail = 1; break; }
            }
        }
        __syncthreads();
        __builtin_amdgcn_fence(__ATOMIC_ACQUIRE, "workgroup"); // no buffer_inv
        __asm__ __volatile__("" ::: "memory");

        // ---- h-part: normal cached loads of write-once slot t (L2 dedups)
        const f16* Ah = h_hi + ((size_t)t * 64 + b) * Hn + ko;
        const f16* Al = h_lo + ((size_t)t * 64 + b) * Hn + ko;
        f32x4 acc1 = {0.f, 0.f, 0.f, 0.f};
        f32x4 acc2 = {0.f, 0.f, 0.f, 0.f};
        f32x4 acc3 = {0.f, 0.f, 0.f, 0.f};
        #pragma unroll 4
        for (int ks = 0; ks < 32; ++ks) {
            f16x8 ah = *(const f16x8*)&Ah[ks * 32];
            f16x8 al = *(const f16x8*)&Al[ks * 32];
            f16x8 bh_ = *(const f16x8*)&Wh_r[ks * 1024];
            f16x8 bl_ = *(const f16x8*)&Wl_r[ks * 1024];
            acc1 = __builtin_amdgcn_mfma_f32_16x16x32_f16(ah, bh_, acc1, 0, 0, 0);
            acc2 = __builtin_amdgcn_mfma_f32_16x16x32_f16(ah, bl_, acc2, 0, 0, 0);
            acc3 = __builtin_amdgcn_mfma_f32_16x16x32_f16(al, bh_, acc3, 0, 0, 0);
        }
        f32x4 acc;
        #pragma unroll
        for (int r = 0; r < 4; ++r)
            acc[r] = (accE[r] + acc1[r]) + (acc2[r] + acc3[r]);

        // ---- cell update. D: col=cl (gate jcol), row=q*4+r
        #pragma unroll
        for (int r = 0; r < 4; ++r) {
            float av = acc[r];
            float iv = __shfl(av, (lane & 48) | co,      64);
            float fv = __shfl(av, (lane & 48) | 4 | co,  64);
            float gv = __shfl(av, (lane & 48) | 8 | co,  64);
            float ov = __shfl(av, (lane & 48) | 12 | co, 64);
            float i_ = fsig(iv);
            float f_ = fsig(fv);
            float g_ = ftanh(gv);
            float o_ = fsig(ov);
            float cn = f_ * cst[r] + i_ * g_;
            cst[r] = cn;
            float hn = o_ * ftanh(cn);
            f16 hh = (f16)hn;
            f16 hl = (f16)(hn - (float)hh);
            unsigned my = (unsigned)__builtin_bit_cast(unsigned short, hh)
                        | ((unsigned)__builtin_bit_cast(unsigned short, hl) << 16);
            // pair-pack with neighbor dim: even co -> h_hi word, odd -> h_lo
            unsigned nb = __shfl(my, lane ^ 1, 64);
            if (cl < 4) {
                unsigned pk = (co & 1) ? ((nb >> 16) | (my & 0xffff0000u))
                                       : ((my & 0xffffu) | (nb << 16));
                unsigned* dstbase = (co & 1) ? (unsigned*)h_lo : (unsigned*)h_hi;
                int d  = d0 + ni * 4 + co;
                int br = bh * 32 + mi * 16 + q * 4 + r;
                __hip_atomic_store(&dstbase[((size_t)(t + 1) * 64 + br) * (Hn / 2) + (d >> 1)],
                                   pk, __ATOMIC_RELAXED, __HIP_MEMORY_SCOPE_AGENT);
            }
        }

        // ---- arrive: __syncthreads drains vmcnt(0) per wave (stores acked)
        __syncthreads();
        __asm__ __volatile__("" ::: "memory");
        if (tid == 0) {
            unsigned prev = __hip_atomic_fetch_add(grp, 1u, __ATOMIC_RELAXED,
                                                   __HIP_MEMORY_SCOPE_AGENT);
            if ((prev & 15u) == 15u)   // 16th arrival of this step in group
                __hip_atomic_fetch_add(root, 1u, __ATOMIC_RELAXED,
                                       __HIP_MEMORY_SCOPE_AGENT);
        }
    }
}

// ---------------------------------------------------------------- energy GEMM
// rows r = t*64+b (h_hi linear row r+64); energy[r] += tanh(row.Wa[d]) * va[d]
__global__ __launch_bounds__(256) void energy_k(
    const f16* __restrict__ h_hi,       // [513*64][1024]
    const f16* __restrict__ Wa_hi,      // [H][H]
    const float* __restrict__ va,       // [H]
    float* __restrict__ energy)         // [B*S] (r-indexed), pre-zeroed
{
    __shared__ f16 Was[128][136];
    const int bid = blockIdx.x;
    const int rb = bid >> 3;
    const int nb = bid & 7;
    const int tid = threadIdx.x;
    const int lane = tid & 63, w = tid >> 6, cl = lane & 15, q = lane >> 4;
    const int r0 = rb * 64 + w * 16 + cl;

    f32x4 acc[8];
    #pragma unroll
    for (int i = 0; i < 8; ++i) acc[i] = (f32x4){0.f, 0.f, 0.f, 0.f};

    for (int kc = 0; kc < 8; ++kc) {
        __syncthreads();
        for (int i = tid; i < 128 * 16; i += 256) {
            int dd = i >> 4;
            int kv = (i & 15) * 8;
            *(f16x8*)&Was[dd][kv] =
                *(const f16x8*)&Wa_hi[(size_t)(nb * 128 + dd) * Hn + kc * 128 + kv];
        }
        __syncthreads();
        const f16* A = h_hi + (size_t)(r0 + 64) * Hn + kc * 128;
        #pragma unroll
        for (int ks = 0; ks < 4; ++ks) {
            f16x8 ah = *(const f16x8*)&A[ks * 32 + q * 8];
            #pragma unroll
            for (int nt = 0; nt < 8; ++nt) {
                f16x8 bb = *(const f16x8*)&Was[nt * 16 + cl][ks * 32 + q * 8];
                acc[nt] = __builtin_amdgcn_mfma_f32_16x16x32_f16(ah, bb, acc[nt], 0, 0, 0);
            }
        }
    }

    float rowsum[4] = {0.f, 0.f, 0.f, 0.f};
    #pragma unroll
    for (int nt = 0; nt < 8; ++nt) {
        float vv = va[nb * 128 + nt * 16 + cl];
        #pragma unroll
        for (int r = 0; r < 4; ++r)
            rowsum[r] += tanhf(acc[nt][r]) * vv;
    }
    #pragma unroll
    for (int m = 1; m < 16; m <<= 1)
        #pragma unroll
        for (int r = 0; r < 4; ++r)
            rowsum[r] += __shfl_xor(rowsum[r], m, 64);
    if (cl == 0) {
        #pragma unroll
        for (int r = 0; r < 4; ++r)
            atomicAdd(&energy[(size_t)rb * 64 + w * 16 + q * 4 + r], rowsum[r]);
    }
}

// ------------------------------------------------- masked softmax + context
// energy index for (b,s) = s*64 + b
__global__ __launch_bounds__(256) void softctx_k(
    const float* __restrict__ energy, const int* __restrict__ x,
    const f16* __restrict__ h_hi, const f16* __restrict__ h_lo,
    float* __restrict__ context)   // [B][H]
{
    __shared__ float sm[512];
    __shared__ float red[256];
    const int b = blockIdx.x, tid = threadIdx.x;
    const int s0 = tid, s1 = tid + 256;
    float e0 = (x[b * Sn + s0] != 0) ? energy[s0 * 64 + b] : -1e10f;
    float e1 = (x[b * Sn + s1] != 0) ? energy[s1 * 64 + b] : -1e10f;
    red[tid] = fmaxf(e0, e1);
    __syncthreads();
    for (int st = 128; st > 0; st >>= 1) {
        if (tid < st) red[tid] = fmaxf(red[tid], red[tid + st]);
        __syncthreads();
    }
    float M = red[0];
    __syncthreads();
    float p0 = expf(e0 - M), p1 = expf(e1 - M);
    red[tid] = p0 + p1;
    __syncthreads();
    for (int st = 128; st > 0; st >>= 1) {
        if (tid < st) red[tid] += red[tid + st];
        __syncthreads();
    }
    float inv = 1.f / red[0];
    sm[s0] = p0 * inv; sm[s1] = p1 * inv;
    __syncthreads();

    const int d0v = tid * 4;
    float a0 = 0.f, a1 = 0.f, a2 = 0.f, a3 = 0.f;
    for (int s = 0; s < Sn; ++s) {
        float at = sm[s];
        size_t row = ((size_t)(s + 1) * 64 + b) * Hn + d0v;
        f16x4 hv = *(const f16x4*)&h_hi[row];
        f16x4 lv = *(const f16x4*)&h_lo[row];
        a0 += at * ((float)hv[0] + (float)lv[0]);
        a1 += at * ((float)hv[1] + (float)lv[1]);
        a2 += at * ((float)hv[2] + (float)lv[2]);
        a3 += at * ((float)hv[3] + (float)lv[3]);
    }
    float* cp = context + (size_t)b * Hn + d0v;
    cp[0] = a0; cp[1] = a1; cp[2] = a2; cp[3] = a3;
}

// ---------------------------------------------------------------- logits
__global__ __launch_bounds__(256) void logits_k(
    const float* __restrict__ context, const float* __restrict__ WV,
    const float* __restrict__ bV, float* __restrict__ out)
{
    __shared__ float red[10][257];
    const int b = blockIdx.x, tid = threadIdx.x;
    const int d0v = tid * 4;
    float4 cv = *(const float4*)&context[(size_t)b * Hn + d0v];
    #pragma unroll
    for (int cls = 0; cls < 10; ++cls) {
        float4 wv = *(const float4*)&WV[cls * Hn + d0v];
        red[cls][tid] = cv.x * wv.x + cv.y * wv.y + cv.z * wv.z + cv.w * wv.w;
    }
    __syncthreads();
    for (int st = 128; st > 0; st >>= 1) {
        if (tid < st)
            #pragma unroll
            for (int cls = 0; cls < 10; ++cls)
                red[cls][tid] += red[cls][tid + st];
        __syncthreads();
    }
    if (tid < 10) out[b * 10 + tid] = red[tid][0] + bV[tid];
}

// ---------------------------------------------------------------- launch
extern "C" void kernel_launch(void* const* d_in, const int* in_sizes, int n_in,
                              void* d_out, int out_size, void* d_ws, size_t ws_size,
                              hipStream_t stream)
{
    const int*   x   = (const int*)d_in[0];
    const float* emb = (const float*)d_in[1];
    const float* Wg  = (const float*)d_in[2];
    const float* bg  = (const float*)d_in[3];
    const float* Wa  = (const float*)d_in[4];
    const float* va  = (const float*)d_in[5];
    const float* WV  = (const float*)d_in[6];
    const float* bV  = (const float*)d_in[7];
    float* out = (float*)d_out;

    char* ws = (char*)d_ws;
    size_t o = 0;
    auto alloc = [&](size_t bytes) { void* p = ws + o; o += (bytes + 255) & ~(size_t)255; return p; };
    f16*      e16   = (f16*)alloc((size_t)Sn * Bn * En * 2);            // 33.5 MB
    f16*      Wa_hi = (f16*)alloc((size_t)Hn * Hn * 2);                 // 2 MB
    f16*      Wge   = (f16*)alloc((size_t)128 * 64 * 32 * 8 * 2);       // 4 MB
    f16*      h_hi  = (f16*)alloc((size_t)(Sn + 1) * Bn * Hn * 2);      // 67.2 MB
    f16*      h_lo  = (f16*)alloc((size_t)(Sn + 1) * Bn * Hn * 2);      // 67.2 MB
    float*    energy= (float*)alloc((size_t)Bn * Sn * 4);
    float*    ctx   = (float*)alloc((size_t)Bn * Hn * 4);
    unsigned* bar   = (unsigned*)alloc(4096);
    // total ~175 MB

    hipMemsetAsync(h_hi, 0, (size_t)Bn * Hn * 2, stream);   // slot 0 = zeros
    hipMemsetAsync(h_lo, 0, (size_t)Bn * Hn * 2, stream);
    hipMemsetAsync(energy, 0, (size_t)Bn * Sn * 4, stream);
    hipMemsetAsync(bar, 0, 4096, stream);

    gather_e_k<<<8192, 256, 0, stream>>>(x, emb, e16);
    split_wa_k<<<512, 256, 0, stream>>>(Wa, Wa_hi);
    wge_prep_k<<<1024, 256, 0, stream>>>(Wg, Wge);

    lstm_persist_k<<<256, 256, 0, stream>>>(e16, Wge, Wg, bg, h_hi, h_lo, bar);

    energy_k<<<512 * 8, 256, 0, stream>>>(h_hi, Wa_hi, va, energy);
    softctx_k<<<Bn, 256, 0, stream>>>(energy, x, h_hi, h_lo, ctx);
    logits_k<<<Bn, 256, 0, stream>>>(ctx, WV, bV, out);
}